// Round 2
// baseline (673.689 us; speedup 1.0000x reference)
//
#include <hip/hip_runtime.h>

#define HIDDEN 4096
#define NH 32
#define NKV 8
#define HD 128
#define LCK 3
#define BB 2
#define SS 1024
#define MTOT (BB * SS)  // 2048

typedef unsigned short u16;
typedef __attribute__((ext_vector_type(8))) short s16x8;   // 8 bf16 (4 VGPRs)
typedef __attribute__((ext_vector_type(4))) short s16x4;   // 4 bf16 (2 VGPRs)
typedef __attribute__((ext_vector_type(4))) float f32x4;

__device__ __forceinline__ u16 f2bf(float f) {  // RNE float->bf16
  unsigned u = __builtin_bit_cast(unsigned, f);
  u += 0x7fffu + ((u >> 16) & 1u);
  return (u16)(u >> 16);
}
__device__ __forceinline__ float bf2f(u16 h) {
  return __builtin_bit_cast(float, (unsigned)h << 16);
}
// async global->LDS, 16B per lane; LDS dest = wave-uniform base + lane*16
__device__ __forceinline__ void gld16(const void* g, void* l) {
  __builtin_amdgcn_global_load_lds((const __attribute__((address_space(1))) void*)g,
                                   (__attribute__((address_space(3))) void*)l, 16, 0, 0);
}

// ---------------------------------------------------------------------------
// fp32 -> bf16 flat convert (hidden_states)
// ---------------------------------------------------------------------------
__global__ __launch_bounds__(256) void convert_h(const float* __restrict__ in,
                                                 u16* __restrict__ out, int n4) {
  int i = blockIdx.x * 256 + threadIdx.x;
  if (i >= n4) return;
  float4 v = ((const float4*)in)[i];
  uint2 o;
  o.x = (unsigned)f2bf(v.x) | ((unsigned)f2bf(v.y) << 16);
  o.y = (unsigned)f2bf(v.z) | ((unsigned)f2bf(v.w) << 16);
  ((uint2*)out)[i] = o;
}

// ---------------------------------------------------------------------------
// W [K][N] fp32  ->  Wt [N][K] bf16   (LDS tile transpose, 64x64)
// ---------------------------------------------------------------------------
__global__ __launch_bounds__(256) void transpose_w(const float* __restrict__ W,
                                                   u16* __restrict__ Wt, int K, int N) {
  __shared__ float tile[64][65];
  const int n0 = blockIdx.x * 64, k0 = blockIdx.y * 64;
  const int ty = threadIdx.x >> 6, tx = threadIdx.x & 63;
#pragma unroll
  for (int i = 0; i < 16; ++i) {
    int r = ty * 16 + i;
    tile[r][tx] = W[(size_t)(k0 + r) * N + n0 + tx];
  }
  __syncthreads();
#pragma unroll
  for (int i = 0; i < 16; ++i) {
    int r = ty * 16 + i;
    Wt[(size_t)(n0 + r) * K + k0 + tx] = f2bf(tile[tx][r]);
  }
}

// ---------------------------------------------------------------------------
// bf16 MFMA GEMM, 256x256 tile / BK=64 / 8 waves (2Mx4N) / 512 threads.
// 8-phase counted-vmcnt schedule + st_16x32 LDS swizzle (see round-0 notes).
// ---------------------------------------------------------------------------
template <bool BF16OUT>
__global__ __launch_bounds__(512, 2) void gemm_bt(
    const u16* __restrict__ A, const u16* __restrict__ Bt,
    void* C0v, void* C1v, void* C2v, int N, int K, int n1, int n2) {
  __shared__ __align__(16) char smem[131072];
  const int tid = threadIdx.x, lane = tid & 63, w = tid >> 6;
  const int wr = w >> 2, wc = w & 3;           // wave -> 128x64 C subtile
  const int col16 = lane & 15, quad = lane >> 4;

  // XCD-aware bijective block swizzle (m204)
  const int nbx = gridDim.x;
  const int nwg = nbx * gridDim.y;
  int fid = blockIdx.y * nbx + blockIdx.x;
  {
    const int q = nwg >> 3, r = nwg & 7;
    const int xcd = fid & 7, lid = fid >> 3;
    fid = (xcd < r ? xcd * (q + 1) : r * (q + 1) + (xcd - r) * q) + lid;
  }
  const int bm = (fid / nbx) << 8, bn = (fid % nbx) << 8;

  const int rowlane = lane >> 2;
  const int collane = ((lane & 3) * 8) ^ ((lane & 32) ? 16 : 0);
  const u16* aSrc = A + (size_t)(bm + ((w >> 1) << 4) + rowlane) * K + ((w & 1) << 5) + collane;
  const u16* bSrc = Bt + (size_t)(bn + ((w >> 1) << 4) + rowlane) * K + ((w & 1) << 5) + collane;
  const int laneoff = (lane & 15) * 64 + (((lane >> 4) << 4) ^ ((lane & 8) << 2));
  const int NT = K >> 6;

#define STG(opOfs, src, buf, h, tt)                                              \
  do {                                                                           \
    gld16((src) + (size_t)((h) * 128) * K + (size_t)(tt) * 64,                   \
          smem + (buf) * 65536 + (opOfs) +                                       \
              ((((h) * 8 + (w >> 1)) * 2 + (w & 1)) << 10));                     \
    gld16((src) + (size_t)((h) * 128 + 64) * K + (size_t)(tt) * 64,              \
          smem + (buf) * 65536 + (opOfs) +                                       \
              ((((h) * 8 + 4 + (w >> 1)) * 2 + (w & 1)) << 10));                 \
  } while (0)
#define BARX asm volatile("s_barrier" ::: "memory")
#define LGK0                                                                     \
  do {                                                                           \
    asm volatile("s_waitcnt lgkmcnt(0)" ::: "memory");                           \
    __builtin_amdgcn_sched_barrier(0);                                           \
  } while (0)

  f32x4 acc[8][4];
#pragma unroll
  for (int f = 0; f < 8; ++f)
#pragma unroll
    for (int g = 0; g < 4; ++g) acc[f][g] = (f32x4){0.f, 0.f, 0.f, 0.f};

  STG(32768, bSrc, 0, 0, 0);
  STG(32768, bSrc, 0, 1, 0);
  STG(0, aSrc, 0, 0, 0);
  STG(0, aSrc, 0, 1, 0);
  STG(32768, bSrc, 1, 0, 1);
  STG(32768, bSrc, 1, 1, 1);
  STG(0, aSrc, 1, 0, 1);
  asm volatile("s_waitcnt vmcnt(6)" ::: "memory");
  BARX;

  for (int kt = 0; kt < NT; ++kt) {
    const int buf = kt & 1;
    const char* Af = smem + buf * 65536 + wr * 16384 + laneoff;
    const char* Bf = smem + buf * 65536 + 32768 + wc * 8192 + laneoff;
    s16x8 b0[4], b1[4], a0[4], a1[4];
    // ---- P1 ----
#pragma unroll
    for (int g = 0; g < 4; ++g) {
      b0[g] = *(const s16x8*)(Bf + (g * 2 + 0) * 1024);
      b1[g] = *(const s16x8*)(Bf + (g * 2 + 1) * 1024);
    }
#pragma unroll
    for (int f = 0; f < 4; ++f) a0[f] = *(const s16x8*)(Af + (f * 2 + 0) * 1024);
    if (kt + 1 < NT) STG(0, aSrc, (kt + 1) & 1, 1, kt + 1);
    BARX; LGK0;
    __builtin_amdgcn_s_setprio(1);
#pragma unroll
    for (int f = 0; f < 4; ++f)
#pragma unroll
      for (int g = 0; g < 4; ++g)
        acc[f][g] = __builtin_amdgcn_mfma_f32_16x16x32_bf16(a0[f], b0[g], acc[f][g], 0, 0, 0);
    __builtin_amdgcn_s_setprio(0);
    BARX;
    // ---- P2 ----
#pragma unroll
    for (int f = 0; f < 4; ++f) a1[f] = *(const s16x8*)(Af + ((4 + f) * 2 + 0) * 1024);
#pragma unroll
    for (int f = 0; f < 4; ++f) a0[f] = *(const s16x8*)(Af + (f * 2 + 1) * 1024);
    if (kt + 2 < NT) STG(32768, bSrc, buf, 0, kt + 2);
    BARX; LGK0;
    __builtin_amdgcn_s_setprio(1);
#pragma unroll
    for (int f = 0; f < 4; ++f)
#pragma unroll
      for (int g = 0; g < 4; ++g)
        acc[4 + f][g] = __builtin_amdgcn_mfma_f32_16x16x32_bf16(a1[f], b0[g], acc[4 + f][g], 0, 0, 0);
    __builtin_amdgcn_s_setprio(0);
    BARX;
    // ---- P3 ----
#pragma unroll
    for (int f = 0; f < 4; ++f) a1[f] = *(const s16x8*)(Af + ((4 + f) * 2 + 1) * 1024);
    if (kt + 2 < NT) STG(32768, bSrc, buf, 1, kt + 2);
    BARX; LGK0;
    __builtin_amdgcn_s_setprio(1);
#pragma unroll
    for (int f = 0; f < 4; ++f)
#pragma unroll
      for (int g = 0; g < 4; ++g)
        acc[f][g] = __builtin_amdgcn_mfma_f32_16x16x32_bf16(a0[f], b1[g], acc[f][g], 0, 0, 0);
    __builtin_amdgcn_s_setprio(0);
    BARX;
    // ---- P4 ----
    if (kt + 2 < NT) STG(0, aSrc, buf, 0, kt + 2);
    BARX; LGK0;
    __builtin_amdgcn_s_setprio(1);
#pragma unroll
    for (int f = 0; f < 4; ++f)
#pragma unroll
      for (int g = 0; g < 4; ++g)
        acc[4 + f][g] = __builtin_amdgcn_mfma_f32_16x16x32_bf16(a1[f], b1[g], acc[4 + f][g], 0, 0, 0);
    __builtin_amdgcn_s_setprio(0);
    if (kt < NT - 2) asm volatile("s_waitcnt vmcnt(6)" ::: "memory");
    else if (kt == NT - 2) asm volatile("s_waitcnt vmcnt(0)" ::: "memory");
    BARX;
  }
#undef STG
#undef BARX
#undef LGK0

  float* Cf; u16* Ch; int ldc, nb;
  if (bn < n1)      { ldc = n1;      nb = bn;      Cf = (float*)C0v; Ch = (u16*)C0v; }
  else if (bn < n2) { ldc = n2 - n1; nb = bn - n1; Cf = (float*)C1v; Ch = (u16*)C1v; }
  else              { ldc = N - n2;  nb = bn - n2; Cf = (float*)C2v; Ch = (u16*)C2v; }
#pragma unroll
  for (int f = 0; f < 8; ++f)
#pragma unroll
    for (int g = 0; g < 4; ++g)
#pragma unroll
      for (int r = 0; r < 4; ++r) {
        size_t off = (size_t)(bm + wr * 128 + f * 16 + quad * 4 + r) * ldc +
                     nb + wc * 64 + g * 16 + col16;
        if (BF16OUT) Ch[off] = f2bf(acc[f][g][r]);
        else         Cf[off] = acc[f][g][r];
      }
}

// ---------------------------------------------------------------------------
// RoPE + relayout: Qbf0 [b][s][32][128] -> Qbf [b][h][s][128] (bf16),
//                  K0bf [b][s][8][128]  -> Kbf [b][kvh][s][128]
// ---------------------------------------------------------------------------
__global__ __launch_bounds__(256) void rope_convert(const u16* __restrict__ Qin,
                                                    const u16* __restrict__ Kin,
                                                    u16* __restrict__ Qout,
                                                    u16* __restrict__ Kout) {
  const int per_row = (NH + NKV) * 64;  // 2560
  int idx = blockIdx.x * 256 + threadIdx.x;
  if (idx >= MTOT * per_row) return;
  int row = idx / per_row;          // b*1024 + s
  int rem = idx - row * per_row;
  int hh = rem >> 6, i = rem & 63;
  int s = row & (SS - 1), b = row >> 10;

  float invf = __expf((float)i * (-9.210340371976184f / 64.0f));
  float ang = (float)s * invf;
  float cv = cosf(ang), sv = sinf(ang);

  if (hh < NH) {
    const u16* src = Qin + (size_t)row * (NH * HD) + hh * HD;
    u16* dst = Qout + (((size_t)(b * NH + hh)) * SS + s) * HD;
    float x0 = bf2f(src[i]), x1 = bf2f(src[i + 64]);
    dst[i] = f2bf(x0 * cv - x1 * sv);
    dst[i + 64] = f2bf(x1 * cv + x0 * sv);
  } else {
    int kh = hh - NH;
    const u16* src = Kin + (size_t)row * (NKV * HD) + kh * HD;
    u16* dst = Kout + (((size_t)(b * NKV + kh)) * SS + s) * HD;
    float x0 = bf2f(src[i]), x1 = bf2f(src[i + 64]);
    dst[i] = f2bf(x0 * cv - x1 * sv);
    dst[i + 64] = f2bf(x1 * cv + x0 * sv);
  }
}

// ---------------------------------------------------------------------------
// V0bf [b][s][8][128] -> Vt [b][kvh][d=128][s=1024]  (bf16 tile transpose)
// ---------------------------------------------------------------------------
__global__ __launch_bounds__(256) void transpose_v(const u16* __restrict__ V0,
                                                   u16* __restrict__ Vt) {
  __shared__ u16 tile[64][65];
  const int s0 = blockIdx.x * 64, d0 = blockIdx.y * 64;
  const int bk = blockIdx.z;  // b*8 + kvh
  const int b = bk >> 3, kvh = bk & 7;
  const int ty = threadIdx.x >> 6, tx = threadIdx.x & 63;
#pragma unroll
  for (int i = 0; i < 16; ++i) {
    int r = ty * 16 + i;
    tile[r][tx] = V0[((size_t)(b * SS + s0 + r)) * (NKV * HD) + kvh * HD + d0 + tx];
  }
  __syncthreads();
#pragma unroll
  for (int i = 0; i < 16; ++i) {
    int r = ty * 16 + i;
    Vt[((size_t)bk * HD + d0 + r) * SS + s0 + tx] = tile[tx][r];
  }
}

// ---------------------------------------------------------------------------
// Flash MFMA attention, barrier-free / LDS-free, swapped-operand.
// Block = 4 waves = 4 GQA heads of one kvh; each wave owns a 16-row q-tile.
// Swapped QK^T: S' = mfma(K, Q) -> lane holds S[k=k0+ks*16+quad*4+r][q=q0+col];
// softmax state (m,l) is one scalar/lane (q=col), row-reduce = local max +
// 2 shfl_xor. PV: P stays in-lane as zero-padded B-operand (k=quad*4+r in
// slots e=0..3 of the quad*8+e mapping), A = V^T 8B frags from global.
// K/V read directly from global (L2-resident at S=1024; no LDS, no barriers).
// Output O[q=col][d=16nt+quad*4+r]. Suffix blocks folded in fp32 epilogue.
// ---------------------------------------------------------------------------
__global__ __launch_bounds__(256) void attn_mfma(
    const u16* __restrict__ Qbf, const u16* __restrict__ Kbf, const u16* __restrict__ Vt,
    const float* __restrict__ ksuf, const float* __restrict__ vsuf,
    u16* __restrict__ AObf, const int* __restrict__ validp) {
  // global heavy-first decomposition: every XCD sees only 2 (b,kvh) K/V sets
  const int bid = (int)blockIdx.x;
  const int qt = 63 - (bid >> 4);
  const int kvh = bid & 7, b = (bid >> 3) & 1;
  const int q0 = qt * 16;
  const int lane = threadIdx.x & 63, w = threadIdx.x >> 6;
  const int col = lane & 15, quad = lane >> 4;
  const int h = (kvh << 2) + w;
  const int valid = *validp;
  const int q = q0 + col;  // this lane's q row (state axis)

  size_t orow = ((size_t)(b * SS + q)) * (NH * HD) + h * HD;
  if (q0 >= valid) {
    ushort4 z = {0, 0, 0, 0};
#pragma unroll
    for (int nt = 0; nt < 8; ++nt)
      *(ushort4*)(AObf + orow + 16 * nt + quad * 4) = z;
    return;
  }

  const float scale = 0.08838834764831845f;  // 1/sqrt(128)
  // Q fragments (B-operand): lane holds Q[q0+col][ds*32+quad*8+e]
  const u16* qptr = Qbf + (((size_t)(b * NH + h)) * SS + q) * HD;
  s16x8 qf[4];
#pragma unroll
  for (int ds = 0; ds < 4; ++ds) qf[ds] = *(const s16x8*)(qptr + ds * 32 + quad * 8);

  const u16* kbase = Kbf + ((size_t)(b * NKV + kvh)) * SS * HD;
  const u16* vbase = Vt + ((size_t)(b * NKV + kvh)) * HD * SS;

  float m_ = -1e30f, l_ = 0.f;
  f32x4 O_[8];
#pragma unroll
  for (int nt = 0; nt < 8; ++nt) O_[nt] = (f32x4){0.f, 0.f, 0.f, 0.f};

  const int ntiles = (q0 + 16 + 63) >> 6;  // KVBLK = 64

  for (int ti = 0; ti < ntiles; ++ti) {
    const int k0 = ti * 64;
    // ---- QK^T (swapped): 4 k-subtiles of 16 ----
    f32x4 S[4];
#pragma unroll
    for (int ks = 0; ks < 4; ++ks) {
      const u16* kp = kbase + (size_t)(k0 + ks * 16 + col) * HD + quad * 8;
      f32x4 s = (f32x4){0.f, 0.f, 0.f, 0.f};
#pragma unroll
      for (int ds = 0; ds < 4; ++ds) {
        s16x8 kf = *(const s16x8*)(kp + ds * 32);
        s = __builtin_amdgcn_mfma_f32_16x16x32_bf16(kf, qf[ds], s, 0, 0, 0);
      }
      S[ks] = s;
    }
    // ---- mask + online softmax (state per lane, q=col) ----
    float sc[16];
    float tm = -1e30f;
#pragma unroll
    for (int ks = 0; ks < 4; ++ks)
#pragma unroll
      for (int r = 0; r < 4; ++r) {
        int kg = k0 + ks * 16 + quad * 4 + r;
        float v = (kg > q) ? -1e30f : S[ks][r] * scale;
        sc[ks * 4 + r] = v;
        tm = fmaxf(tm, v);
      }
    tm = fmaxf(tm, __shfl_xor(tm, 16));
    tm = fmaxf(tm, __shfl_xor(tm, 32));
    float mn = fmaxf(m_, tm);
    float a = __expf(m_ - mn);
    float pv[16];
    float rs = 0.f;
#pragma unroll
    for (int i = 0; i < 16; ++i) {
      pv[i] = __expf(sc[i] - mn);
      rs += pv[i];
    }
    rs += __shfl_xor(rs, 16);
    rs += __shfl_xor(rs, 32);
    l_ = l_ * a + rs;
    m_ = mn;
#pragma unroll
    for (int nt = 0; nt < 8; ++nt)
#pragma unroll
      for (int r = 0; r < 4; ++r) O_[nt][r] *= a;

    // ---- PV: zero-padded B-operand, A = V^T 8B frags from global ----
#pragma unroll
    for (int ks = 0; ks < 4; ++ks) {
      s16x8 pb;
      pb[0] = (short)f2bf(pv[ks * 4 + 0]);
      pb[1] = (short)f2bf(pv[ks * 4 + 1]);
      pb[2] = (short)f2bf(pv[ks * 4 + 2]);
      pb[3] = (short)f2bf(pv[ks * 4 + 3]);
      pb[4] = 0; pb[5] = 0; pb[6] = 0; pb[7] = 0;
      const u16* vp0 = vbase + (size_t)col * SS + k0 + ks * 16 + quad * 4;
#pragma unroll
      for (int nt = 0; nt < 8; ++nt) {
        s16x4 vv = *(const s16x4*)(vp0 + (size_t)(16 * nt) * SS);
        s16x8 av;
        av[0] = vv[0]; av[1] = vv[1]; av[2] = vv[2]; av[3] = vv[3];
        av[4] = 0; av[5] = 0; av[6] = 0; av[7] = 0;
        O_[nt] = __builtin_amdgcn_mfma_f32_16x16x32_bf16(av, pb, O_[nt], 0, 0, 0);
      }
    }
  }

  // ---- suffix blocks (diagonal kv = q), fp32, folded into online softmax ----
  float sp[3];
#pragma unroll
  for (int j = 0; j < 3; ++j) {
    const float* kr = ksuf + ((((size_t)(b * NKV + kvh) * LCK + j)) * SS + q) * HD + quad * 8;
    float p = 0.f;
#pragma unroll
    for (int ds = 0; ds < 4; ++ds)
#pragma unroll
      for (int e = 0; e < 8; ++e) p += bf2f((u16)qf[ds][e]) * kr[ds * 32 + e];
    p += __shfl_xor(p, 16);
    p += __shfl_xor(p, 32);
    sp[j] = p * scale;
  }
  {
    float ms = fmaxf(fmaxf(sp[0], sp[1]), sp[2]);
    float mn = fmaxf(m_, ms);
    float a = __expf(m_ - mn);
    float e0 = __expf(sp[0] - mn);
    float e1 = __expf(sp[1] - mn);
    float e2 = __expf(sp[2] - mn);
    l_ = l_ * a + e0 + e1 + e2;
    const float* v0r = vsuf + ((((size_t)(b * NKV + kvh) * LCK + 0)) * SS + q) * HD + quad * 4;
    const float* v1r = v0r + (size_t)SS * HD;
    const float* v2r = v1r + (size_t)SS * HD;
#pragma unroll
    for (int nt = 0; nt < 8; ++nt) {
      float4 x0 = *(const float4*)(v0r + 16 * nt);
      float4 x1 = *(const float4*)(v1r + 16 * nt);
      float4 x2 = *(const float4*)(v2r + 16 * nt);
      O_[nt][0] = O_[nt][0] * a + e0 * x0.x + e1 * x1.x + e2 * x2.x;
      O_[nt][1] = O_[nt][1] * a + e0 * x0.y + e1 * x1.y + e2 * x2.y;
      O_[nt][2] = O_[nt][2] * a + e0 * x0.z + e1 * x1.z + e2 * x2.z;
      O_[nt][3] = O_[nt][3] * a + e0 * x0.w + e1 * x1.w + e2 * x2.w;
    }
  }

  // ---- write AObf [b][s][h][d] (bf16); rows >= valid are zero ----
  if (q >= valid) {
    ushort4 z = {0, 0, 0, 0};
#pragma unroll
    for (int nt = 0; nt < 8; ++nt)
      *(ushort4*)(AObf + orow + 16 * nt + quad * 4) = z;
  } else {
    float inv = 1.f / l_;
#pragma unroll
    for (int nt = 0; nt < 8; ++nt) {
      ushort4 o;
      o.x = f2bf(O_[nt][0] * inv);
      o.y = f2bf(O_[nt][1] * inv);
      o.z = f2bf(O_[nt][2] * inv);
      o.w = f2bf(O_[nt][3] * inv);
      *(ushort4*)(AObf + orow + 16 * nt + quad * 4) = o;
    }
  }
}

// ---------------------------------------------------------------------------
extern "C" void kernel_launch(void* const* d_in, const int* in_sizes, int n_in,
                              void* d_out, int out_size, void* d_ws, size_t ws_size,
                              hipStream_t stream) {
  const float* hidden = (const float*)d_in[0];
  const float* ksuf = (const float*)d_in[1];
  const float* vsuf = (const float*)d_in[2];
  const float* Wq = (const float*)d_in[3];
  const float* Wk = (const float*)d_in[4];
  const float* Wv = (const float*)d_in[5];
  const float* Wo = (const float*)d_in[6];
  const int* validp = (const int*)d_in[7];
  float* out = (float*)d_out;

  // workspace layout (96MB peak, regions aliased across phases)
  char* W = (char*)d_ws;
  u16* Hbf  = (u16*)(W + 0);                     // 16MB  (dead after QKV gemm)
  u16* WqT  = (u16*)(W + ((size_t)16 << 20));    // 32MB  (WqT|WkT|WvT contiguous [6144][4096])
  u16* WkT  = (u16*)(W + ((size_t)48 << 20));    // 8MB
  u16* WvT  = (u16*)(W + ((size_t)56 << 20));    // 8MB
  u16* Qbf0 = (u16*)(W + ((size_t)64 << 20));    // 16MB  (dead after rope)
  u16* K0bf = (u16*)(W + ((size_t)80 << 20));    // 4MB
  u16* V0bf = (u16*)(W + ((size_t)84 << 20));    // 4MB
  u16* Kbf  = (u16*)(W + ((size_t)88 << 20));    // 4MB
  u16* Vt   = (u16*)(W + ((size_t)92 << 20));    // 4MB
  u16* Qbf  = (u16*)(W + 0);                     // alias Hbf
  u16* WoT  = (u16*)(W + ((size_t)16 << 20));    // alias WqT
  u16* AObf = (u16*)(W + ((size_t)64 << 20));    // alias Qbf0

  // 1. convert hidden -> bf16
  convert_h<<<(MTOT * HIDDEN / 4 + 255) / 256, 256, 0, stream>>>(hidden, Hbf, MTOT * HIDDEN / 4);
  // 2. transpose+convert projection weights (B^T for gemm)
  transpose_w<<<dim3(64, 64), 256, 0, stream>>>(Wq, WqT, HIDDEN, NH * HD);
  transpose_w<<<dim3(16, 64), 256, 0, stream>>>(Wk, WkT, HIDDEN, NKV * HD);
  transpose_w<<<dim3(16, 64), 256, 0, stream>>>(Wv, WvT, HIDDEN, NKV * HD);
  // 3. fused QKV projection: N = 4096+1024+1024, bf16 out (256x256 tiles)
  gemm_bt<true><<<dim3(24, 8), 512, 0, stream>>>(
      Hbf, WqT, Qbf0, K0bf, V0bf, 6144, HIDDEN, 4096, 5120);
  // 4. Wo transpose (into dead WqT region)
  transpose_w<<<dim3(64, 64), 256, 0, stream>>>(Wo, WoT, NH * HD, HIDDEN);
  // 5. RoPE + head-major relayout (Qbf over dead Hbf)
  rope_convert<<<(MTOT * (NH + NKV) * 64 + 255) / 256, 256, 0, stream>>>(Qbf0, K0bf, Qbf, Kbf);
  // 6. V transpose to [b][kvh][d][s]
  transpose_v<<<dim3(16, 2, BB * NKV), 256, 0, stream>>>(V0bf, Vt);
  // 7. flash MFMA attention (AObf over dead Qbf0) — 1D heavy-first grid
  attn_mfma<<<dim3(1024), 256, 0, stream>>>(Qbf, Kbf, Vt, ksuf, vsuf, AObf, validp);
  // 8. output projection (fp32 out, 256x256 tiles)
  gemm_bt<false><<<dim3(16, 8), 512, 0, stream>>>(
      AObf, WoT, out, out, out, HIDDEN, NH * HD, 4096, 4096);
}

// Round 3
// 538.479 us; speedup vs baseline: 1.2511x; 1.2511x over previous
//
#include <hip/hip_runtime.h>

#define HIDDEN 4096
#define NH 32
#define NKV 8
#define HD 128
#define LCK 3
#define BB 2
#define SS 1024
#define MTOT (BB * SS)  // 2048

typedef unsigned short u16;
typedef __attribute__((ext_vector_type(8))) short s16x8;   // 8 bf16 (4 VGPRs)
typedef __attribute__((ext_vector_type(4))) short s16x4;   // 4 bf16 (2 VGPRs)
typedef __attribute__((ext_vector_type(4))) float f32x4;

__device__ __forceinline__ u16 f2bf(float f) {  // RNE float->bf16
  unsigned u = __builtin_bit_cast(unsigned, f);
  u += 0x7fffu + ((u >> 16) & 1u);
  return (u16)(u >> 16);
}
__device__ __forceinline__ float bf2f(u16 h) {
  return __builtin_bit_cast(float, (unsigned)h << 16);
}
// async global->LDS, 16B per lane; LDS dest = wave-uniform base + lane*16
__device__ __forceinline__ void gld16(const void* g, void* l) {
  __builtin_amdgcn_global_load_lds((const __attribute__((address_space(1))) void*)g,
                                   (__attribute__((address_space(3))) void*)l, 16, 0, 0);
}

// ---------------------------------------------------------------------------
// fp32 -> bf16 flat convert (hidden_states)
// ---------------------------------------------------------------------------
__global__ __launch_bounds__(256) void convert_h(const float* __restrict__ in,
                                                 u16* __restrict__ out, int n4) {
  int i = blockIdx.x * 256 + threadIdx.x;
  if (i >= n4) return;
  float4 v = ((const float4*)in)[i];
  uint2 o;
  o.x = (unsigned)f2bf(v.x) | ((unsigned)f2bf(v.y) << 16);
  o.y = (unsigned)f2bf(v.z) | ((unsigned)f2bf(v.w) << 16);
  ((uint2*)out)[i] = o;
}

// ---------------------------------------------------------------------------
// W [K][N] fp32  ->  Wt [N][K] bf16   (LDS tile transpose, 64x64)
// ---------------------------------------------------------------------------
__global__ __launch_bounds__(256) void transpose_w(const float* __restrict__ W,
                                                   u16* __restrict__ Wt, int K, int N) {
  __shared__ float tile[64][65];
  const int n0 = blockIdx.x * 64, k0 = blockIdx.y * 64;
  const int ty = threadIdx.x >> 6, tx = threadIdx.x & 63;
#pragma unroll
  for (int i = 0; i < 16; ++i) {
    int r = ty * 16 + i;
    tile[r][tx] = W[(size_t)(k0 + r) * N + n0 + tx];
  }
  __syncthreads();
#pragma unroll
  for (int i = 0; i < 16; ++i) {
    int r = ty * 16 + i;
    Wt[(size_t)(n0 + r) * K + k0 + tx] = f2bf(tile[tx][r]);
  }
}

// ---------------------------------------------------------------------------
// bf16 MFMA GEMM, 256x256 tile / BK=64 / 8 waves (2Mx4N) / 512 threads.
// 8-phase counted-vmcnt schedule + st_16x32 LDS swizzle (see round-0 notes).
// ---------------------------------------------------------------------------
template <bool BF16OUT>
__global__ __launch_bounds__(512, 2) void gemm_bt(
    const u16* __restrict__ A, const u16* __restrict__ Bt,
    void* C0v, void* C1v, void* C2v, int N, int K, int n1, int n2) {
  __shared__ __align__(16) char smem[131072];
  const int tid = threadIdx.x, lane = tid & 63, w = tid >> 6;
  const int wr = w >> 2, wc = w & 3;           // wave -> 128x64 C subtile
  const int col16 = lane & 15, quad = lane >> 4;

  // XCD-aware bijective block swizzle (m204)
  const int nbx = gridDim.x;
  const int nwg = nbx * gridDim.y;
  int fid = blockIdx.y * nbx + blockIdx.x;
  {
    const int q = nwg >> 3, r = nwg & 7;
    const int xcd = fid & 7, lid = fid >> 3;
    fid = (xcd < r ? xcd * (q + 1) : r * (q + 1) + (xcd - r) * q) + lid;
  }
  const int bm = (fid / nbx) << 8, bn = (fid % nbx) << 8;

  const int rowlane = lane >> 2;
  const int collane = ((lane & 3) * 8) ^ ((lane & 32) ? 16 : 0);
  const u16* aSrc = A + (size_t)(bm + ((w >> 1) << 4) + rowlane) * K + ((w & 1) << 5) + collane;
  const u16* bSrc = Bt + (size_t)(bn + ((w >> 1) << 4) + rowlane) * K + ((w & 1) << 5) + collane;
  const int laneoff = (lane & 15) * 64 + (((lane >> 4) << 4) ^ ((lane & 8) << 2));
  const int NT = K >> 6;

#define STG(opOfs, src, buf, h, tt)                                              \
  do {                                                                           \
    gld16((src) + (size_t)((h) * 128) * K + (size_t)(tt) * 64,                   \
          smem + (buf) * 65536 + (opOfs) +                                       \
              ((((h) * 8 + (w >> 1)) * 2 + (w & 1)) << 10));                     \
    gld16((src) + (size_t)((h) * 128 + 64) * K + (size_t)(tt) * 64,              \
          smem + (buf) * 65536 + (opOfs) +                                       \
              ((((h) * 8 + 4 + (w >> 1)) * 2 + (w & 1)) << 10));                 \
  } while (0)
#define BARX asm volatile("s_barrier" ::: "memory")
#define LGK0                                                                     \
  do {                                                                           \
    asm volatile("s_waitcnt lgkmcnt(0)" ::: "memory");                           \
    __builtin_amdgcn_sched_barrier(0);                                           \
  } while (0)

  f32x4 acc[8][4];
#pragma unroll
  for (int f = 0; f < 8; ++f)
#pragma unroll
    for (int g = 0; g < 4; ++g) acc[f][g] = (f32x4){0.f, 0.f, 0.f, 0.f};

  STG(32768, bSrc, 0, 0, 0);
  STG(32768, bSrc, 0, 1, 0);
  STG(0, aSrc, 0, 0, 0);
  STG(0, aSrc, 0, 1, 0);
  STG(32768, bSrc, 1, 0, 1);
  STG(32768, bSrc, 1, 1, 1);
  STG(0, aSrc, 1, 0, 1);
  asm volatile("s_waitcnt vmcnt(6)" ::: "memory");
  BARX;

  for (int kt = 0; kt < NT; ++kt) {
    const int buf = kt & 1;
    const char* Af = smem + buf * 65536 + wr * 16384 + laneoff;
    const char* Bf = smem + buf * 65536 + 32768 + wc * 8192 + laneoff;
    s16x8 b0[4], b1[4], a0[4], a1[4];
    // ---- P1 ----
#pragma unroll
    for (int g = 0; g < 4; ++g) {
      b0[g] = *(const s16x8*)(Bf + (g * 2 + 0) * 1024);
      b1[g] = *(const s16x8*)(Bf + (g * 2 + 1) * 1024);
    }
#pragma unroll
    for (int f = 0; f < 4; ++f) a0[f] = *(const s16x8*)(Af + (f * 2 + 0) * 1024);
    if (kt + 1 < NT) STG(0, aSrc, (kt + 1) & 1, 1, kt + 1);
    BARX; LGK0;
    __builtin_amdgcn_s_setprio(1);
#pragma unroll
    for (int f = 0; f < 4; ++f)
#pragma unroll
      for (int g = 0; g < 4; ++g)
        acc[f][g] = __builtin_amdgcn_mfma_f32_16x16x32_bf16(a0[f], b0[g], acc[f][g], 0, 0, 0);
    __builtin_amdgcn_s_setprio(0);
    BARX;
    // ---- P2 ----
#pragma unroll
    for (int f = 0; f < 4; ++f) a1[f] = *(const s16x8*)(Af + ((4 + f) * 2 + 0) * 1024);
#pragma unroll
    for (int f = 0; f < 4; ++f) a0[f] = *(const s16x8*)(Af + (f * 2 + 1) * 1024);
    if (kt + 2 < NT) STG(32768, bSrc, buf, 0, kt + 2);
    BARX; LGK0;
    __builtin_amdgcn_s_setprio(1);
#pragma unroll
    for (int f = 0; f < 4; ++f)
#pragma unroll
      for (int g = 0; g < 4; ++g)
        acc[4 + f][g] = __builtin_amdgcn_mfma_f32_16x16x32_bf16(a1[f], b0[g], acc[4 + f][g], 0, 0, 0);
    __builtin_amdgcn_s_setprio(0);
    BARX;
    // ---- P3 ----
#pragma unroll
    for (int f = 0; f < 4; ++f) a1[f] = *(const s16x8*)(Af + ((4 + f) * 2 + 1) * 1024);
    if (kt + 2 < NT) STG(32768, bSrc, buf, 1, kt + 2);
    BARX; LGK0;
    __builtin_amdgcn_s_setprio(1);
#pragma unroll
    for (int f = 0; f < 4; ++f)
#pragma unroll
      for (int g = 0; g < 4; ++g)
        acc[f][g] = __builtin_amdgcn_mfma_f32_16x16x32_bf16(a0[f], b1[g], acc[f][g], 0, 0, 0);
    __builtin_amdgcn_s_setprio(0);
    BARX;
    // ---- P4 ----
    if (kt + 2 < NT) STG(0, aSrc, buf, 0, kt + 2);
    BARX; LGK0;
    __builtin_amdgcn_s_setprio(1);
#pragma unroll
    for (int f = 0; f < 4; ++f)
#pragma unroll
      for (int g = 0; g < 4; ++g)
        acc[4 + f][g] = __builtin_amdgcn_mfma_f32_16x16x32_bf16(a1[f], b1[g], acc[4 + f][g], 0, 0, 0);
    __builtin_amdgcn_s_setprio(0);
    if (kt < NT - 2) asm volatile("s_waitcnt vmcnt(6)" ::: "memory");
    else if (kt == NT - 2) asm volatile("s_waitcnt vmcnt(0)" ::: "memory");
    BARX;
  }
#undef STG
#undef BARX
#undef LGK0

  float* Cf; u16* Ch; int ldc, nb;
  if (bn < n1)      { ldc = n1;      nb = bn;      Cf = (float*)C0v; Ch = (u16*)C0v; }
  else if (bn < n2) { ldc = n2 - n1; nb = bn - n1; Cf = (float*)C1v; Ch = (u16*)C1v; }
  else              { ldc = N - n2;  nb = bn - n2; Cf = (float*)C2v; Ch = (u16*)C2v; }
#pragma unroll
  for (int f = 0; f < 8; ++f)
#pragma unroll
    for (int g = 0; g < 4; ++g)
#pragma unroll
      for (int r = 0; r < 4; ++r) {
        size_t off = (size_t)(bm + wr * 128 + f * 16 + quad * 4 + r) * ldc +
                     nb + wc * 64 + g * 16 + col16;
        if (BF16OUT) Ch[off] = f2bf(acc[f][g][r]);
        else         Cf[off] = acc[f][g][r];
      }
}

// ---------------------------------------------------------------------------
// RoPE + relayout: Qbf0 [b][s][32][128] -> Qbf [b][h][s][128] (bf16),
//                  K0bf [b][s][8][128]  -> Kbf [b][kvh][s][128]
// ---------------------------------------------------------------------------
__global__ __launch_bounds__(256) void rope_convert(const u16* __restrict__ Qin,
                                                    const u16* __restrict__ Kin,
                                                    u16* __restrict__ Qout,
                                                    u16* __restrict__ Kout) {
  const int per_row = (NH + NKV) * 64;  // 2560
  int idx = blockIdx.x * 256 + threadIdx.x;
  if (idx >= MTOT * per_row) return;
  int row = idx / per_row;          // b*1024 + s
  int rem = idx - row * per_row;
  int hh = rem >> 6, i = rem & 63;
  int s = row & (SS - 1), b = row >> 10;

  float invf = __expf((float)i * (-9.210340371976184f / 64.0f));
  float ang = (float)s * invf;
  float cv = cosf(ang), sv = sinf(ang);

  if (hh < NH) {
    const u16* src = Qin + (size_t)row * (NH * HD) + hh * HD;
    u16* dst = Qout + (((size_t)(b * NH + hh)) * SS + s) * HD;
    float x0 = bf2f(src[i]), x1 = bf2f(src[i + 64]);
    dst[i] = f2bf(x0 * cv - x1 * sv);
    dst[i + 64] = f2bf(x1 * cv + x0 * sv);
  } else {
    int kh = hh - NH;
    const u16* src = Kin + (size_t)row * (NKV * HD) + kh * HD;
    u16* dst = Kout + (((size_t)(b * NKV + kh)) * SS + s) * HD;
    float x0 = bf2f(src[i]), x1 = bf2f(src[i + 64]);
    dst[i] = f2bf(x0 * cv - x1 * sv);
    dst[i + 64] = f2bf(x1 * cv + x0 * sv);
  }
}

// ---------------------------------------------------------------------------
// V0bf [b][s][8][128] -> Vt [b][kvh][d=128][s=1024]  (bf16 tile transpose)
// ---------------------------------------------------------------------------
__global__ __launch_bounds__(256) void transpose_v(const u16* __restrict__ V0,
                                                   u16* __restrict__ Vt) {
  __shared__ u16 tile[64][65];
  const int s0 = blockIdx.x * 64, d0 = blockIdx.y * 64;
  const int bk = blockIdx.z;  // b*8 + kvh
  const int b = bk >> 3, kvh = bk & 7;
  const int ty = threadIdx.x >> 6, tx = threadIdx.x & 63;
#pragma unroll
  for (int i = 0; i < 16; ++i) {
    int r = ty * 16 + i;
    tile[r][tx] = V0[((size_t)(b * SS + s0 + r)) * (NKV * HD) + kvh * HD + d0 + tx];
  }
  __syncthreads();
#pragma unroll
  for (int i = 0; i < 16; ++i) {
    int r = ty * 16 + i;
    Vt[((size_t)bk * HD + d0 + r) * SS + s0 + tx] = tile[tx][r];
  }
}

// ---------------------------------------------------------------------------
// Flash MFMA attention: swapped-operand (round-2 verified math) + LDS-staged
// K/V (double-buffered, 2-phase pipeline, 1 barrier per KV-64 tile).
// Block = 4 waves = 4 GQA heads of one kvh; each wave owns a 16-row q-tile.
// Swapped QK^T: S' = mfma(K, Q) -> lane holds S[k=k0+16ks+quad*4+r][q=q0+col];
// per-lane softmax state (q=col), reduce = 2 shfl_xor. PV zero-padded B frag.
// LDS XOR-swizzle (c ^= (row&7)<<4) applied on BOTH the gld16 global source
// (linear LDS dest) and the ds_read address (rule #21 involution):
//   K buf [64][128] bf16 : read rows stride 256B -> conflict-free after swz.
//   V^T buf [128][64] bf16: read rows stride 128B -> conflict-free after swz.
// ---------------------------------------------------------------------------
__global__ __launch_bounds__(256) void attn_mfma(
    const u16* __restrict__ Qbf, const u16* __restrict__ Kbf, const u16* __restrict__ Vt,
    const float* __restrict__ ksuf, const float* __restrict__ vsuf,
    u16* __restrict__ AObf, const int* __restrict__ validp) {
  __shared__ __align__(16) char Ksm[2][16384];  // [buf][k=64][dbyte=256 swz]
  __shared__ __align__(16) char Vsm[2][16384];  // [buf][d=128][kbyte=128 swz]

  // heavy-first decomposition: every XCD sees only 2 (b,kvh) K/V sets
  const int bid = (int)blockIdx.x;
  const int qt = 63 - (bid >> 4);
  const int kvh = bid & 7, b = (bid >> 3) & 1;
  const int q0 = qt * 16;
  const int lane = threadIdx.x & 63, w = threadIdx.x >> 6;
  const int col = lane & 15, quad = lane >> 4;
  const int h = (kvh << 2) + w;
  const int valid = *validp;
  const int q = q0 + col;  // this lane's q row (state axis)

  size_t orow = ((size_t)(b * SS + q)) * (NH * HD) + h * HD;
  if (q0 >= valid) {  // block-uniform early out (no barriers executed)
    ushort4 z = {0, 0, 0, 0};
#pragma unroll
    for (int nt = 0; nt < 8; ++nt)
      *(ushort4*)(AObf + orow + 16 * nt + quad * 4) = z;
    return;
  }

  const float scale = 0.08838834764831845f;  // 1/sqrt(128)
  // Q fragments (B-operand): lane holds Q[q0+col][ds*32+quad*8+e]
  const u16* qptr = Qbf + (((size_t)(b * NH + h)) * SS + q) * HD;
  s16x8 qf[4];
#pragma unroll
  for (int ds = 0; ds < 4; ++ds) qf[ds] = *(const s16x8*)(qptr + ds * 32 + quad * 8);

  const u16* kbase = Kbf + ((size_t)(b * NKV + kvh)) * SS * HD;
  const u16* vbase = Vt + ((size_t)(b * NKV + kvh)) * HD * SS;

  // staging source offsets (elements, relative to tile origin), pre-swizzled.
  // K chunk j: LDS Y=j*4096+w*1024+lane*16 -> k=j*16+w*4+quad, c=col*16.
  //            src elem = k*128 + ((col*16 ^ ((k&7)<<4))>>1)
  // V chunk j: Y -> d=j*32+w*8+(lane>>3), c=(lane&7)*16.
  //            src elem = d*SS + (((lane&7)*16 ^ ((d&7)<<4))>>1)
  int ksrcoff[4], vsrcoff[4];
  {
    const int kq = (w * 4 + quad) & 7;
    const int dq = (lane >> 3) & 7;
#pragma unroll
    for (int j = 0; j < 4; ++j) {
      int kl = j * 16 + w * 4 + quad;
      ksrcoff[j] = kl * HD + (((col * 16) ^ (kq << 4)) >> 1);
      int dl = j * 32 + w * 8 + (lane >> 3);
      vsrcoff[j] = dl * SS + ((((lane & 7) * 16) ^ (dq << 4)) >> 1);
    }
  }

#define STAGE(bufi, k0v)                                                        \
  do {                                                                          \
    const u16* kp_ = kbase + (size_t)(k0v)*HD;                                  \
    const u16* vp_ = vbase + (k0v);                                             \
    _Pragma("unroll") for (int j = 0; j < 4; ++j)                               \
        gld16(kp_ + ksrcoff[j], Ksm[bufi] + j * 4096 + w * 1024);               \
    _Pragma("unroll") for (int j = 0; j < 4; ++j)                               \
        gld16(vp_ + vsrcoff[j], Vsm[bufi] + j * 4096 + w * 1024);               \
  } while (0)

  float m_ = -1e30f, l_ = 0.f;
  f32x4 O_[8];
#pragma unroll
  for (int nt = 0; nt < 8; ++nt) O_[nt] = (f32x4){0.f, 0.f, 0.f, 0.f};

  const int ntiles = (q0 + 16 + 63) >> 6;  // KVBLK = 64
  const int kswz = (col & 7) << 4;

  STAGE(0, 0);
  __syncthreads();

  for (int ti = 0; ti < ntiles; ++ti) {
    const int k0 = ti * 64;
    if (ti + 1 < ntiles) STAGE((ti + 1) & 1, k0 + 64);  // prefetch next tile
    const char* Kb = Ksm[ti & 1];
    const char* Vb = Vsm[ti & 1];

    // ---- QK^T (swapped): 4 k-subtiles of 16, A = K frag from swizzled LDS ----
    f32x4 S[4];
#pragma unroll
    for (int ks = 0; ks < 4; ++ks) {
      f32x4 s = (f32x4){0.f, 0.f, 0.f, 0.f};
#pragma unroll
      for (int ds = 0; ds < 4; ++ds) {
        s16x8 kf = *(const s16x8*)(Kb + ks * 4096 + col * 256 +
                                   ((ds * 64 + quad * 16) ^ kswz));
        s = __builtin_amdgcn_mfma_f32_16x16x32_bf16(kf, qf[ds], s, 0, 0, 0);
      }
      S[ks] = s;
    }
    // ---- mask + online softmax (state per lane, q=col) ----
    float sc[16];
    float tm = -1e30f;
#pragma unroll
    for (int ks = 0; ks < 4; ++ks)
#pragma unroll
      for (int r = 0; r < 4; ++r) {
        int kg = k0 + ks * 16 + quad * 4 + r;
        float v = (kg > q) ? -1e30f : S[ks][r] * scale;
        sc[ks * 4 + r] = v;
        tm = fmaxf(tm, v);
      }
    tm = fmaxf(tm, __shfl_xor(tm, 16));
    tm = fmaxf(tm, __shfl_xor(tm, 32));
    float mn = fmaxf(m_, tm);
    float a = __expf(m_ - mn);
    float pv[16];
    float rs = 0.f;
#pragma unroll
    for (int i = 0; i < 16; ++i) {
      pv[i] = __expf(sc[i] - mn);
      rs += pv[i];
    }
    rs += __shfl_xor(rs, 16);
    rs += __shfl_xor(rs, 32);
    l_ = l_ * a + rs;
    m_ = mn;
#pragma unroll
    for (int nt = 0; nt < 8; ++nt)
#pragma unroll
      for (int r = 0; r < 4; ++r) O_[nt][r] *= a;

    // ---- PV: zero-padded B frag, A = V^T 8B frags from swizzled LDS ----
#pragma unroll
    for (int ks = 0; ks < 4; ++ks) {
      s16x8 pb;
      pb[0] = (short)f2bf(pv[ks * 4 + 0]);
      pb[1] = (short)f2bf(pv[ks * 4 + 1]);
      pb[2] = (short)f2bf(pv[ks * 4 + 2]);
      pb[3] = (short)f2bf(pv[ks * 4 + 3]);
      pb[4] = 0; pb[5] = 0; pb[6] = 0; pb[7] = 0;
#pragma unroll
      for (int nt = 0; nt < 8; ++nt) {
        s16x4 vv = *(const s16x4*)(Vb + nt * 2048 + col * 128 +
                                   ((ks * 32 + quad * 8) ^ kswz));
        s16x8 av;
        av[0] = vv[0]; av[1] = vv[1]; av[2] = vv[2]; av[3] = vv[3];
        av[4] = 0; av[5] = 0; av[6] = 0; av[7] = 0;
        O_[nt] = __builtin_amdgcn_mfma_f32_16x16x32_bf16(av, pb, O_[nt], 0, 0, 0);
      }
    }
    __syncthreads();  // drains prefetch (vmcnt 0) + releases buf for overwrite
  }
#undef STAGE

  // ---- suffix blocks (diagonal kv = q), fp32, folded into online softmax ----
  float sp[3];
#pragma unroll
  for (int j = 0; j < 3; ++j) {
    const float* kr = ksuf + ((((size_t)(b * NKV + kvh) * LCK + j)) * SS + q) * HD + quad * 8;
    float p = 0.f;
#pragma unroll
    for (int ds = 0; ds < 4; ++ds)
#pragma unroll
      for (int e = 0; e < 8; ++e) p += bf2f((u16)qf[ds][e]) * kr[ds * 32 + e];
    p += __shfl_xor(p, 16);
    p += __shfl_xor(p, 32);
    sp[j] = p * scale;
  }
  {
    float ms = fmaxf(fmaxf(sp[0], sp[1]), sp[2]);
    float mn = fmaxf(m_, ms);
    float a = __expf(m_ - mn);
    float e0 = __expf(sp[0] - mn);
    float e1 = __expf(sp[1] - mn);
    float e2 = __expf(sp[2] - mn);
    l_ = l_ * a + e0 + e1 + e2;
    const float* v0r = vsuf + ((((size_t)(b * NKV + kvh) * LCK + 0)) * SS + q) * HD + quad * 4;
    const float* v1r = v0r + (size_t)SS * HD;
    const float* v2r = v1r + (size_t)SS * HD;
#pragma unroll
    for (int nt = 0; nt < 8; ++nt) {
      float4 x0 = *(const float4*)(v0r + 16 * nt);
      float4 x1 = *(const float4*)(v1r + 16 * nt);
      float4 x2 = *(const float4*)(v2r + 16 * nt);
      O_[nt][0] = O_[nt][0] * a + e0 * x0.x + e1 * x1.x + e2 * x2.x;
      O_[nt][1] = O_[nt][1] * a + e0 * x0.y + e1 * x1.y + e2 * x2.y;
      O_[nt][2] = O_[nt][2] * a + e0 * x0.z + e1 * x1.z + e2 * x2.z;
      O_[nt][3] = O_[nt][3] * a + e0 * x0.w + e1 * x1.w + e2 * x2.w;
    }
  }

  // ---- write AObf [b][s][h][d] (bf16); rows >= valid are zero ----
  if (q >= valid) {
    ushort4 z = {0, 0, 0, 0};
#pragma unroll
    for (int nt = 0; nt < 8; ++nt)
      *(ushort4*)(AObf + orow + 16 * nt + quad * 4) = z;
  } else {
    float inv = 1.f / l_;
#pragma unroll
    for (int nt = 0; nt < 8; ++nt) {
      ushort4 o;
      o.x = f2bf(O_[nt][0] * inv);
      o.y = f2bf(O_[nt][1] * inv);
      o.z = f2bf(O_[nt][2] * inv);
      o.w = f2bf(O_[nt][3] * inv);
      *(ushort4*)(AObf + orow + 16 * nt + quad * 4) = o;
    }
  }
}

// ---------------------------------------------------------------------------
extern "C" void kernel_launch(void* const* d_in, const int* in_sizes, int n_in,
                              void* d_out, int out_size, void* d_ws, size_t ws_size,
                              hipStream_t stream) {
  const float* hidden = (const float*)d_in[0];
  const float* ksuf = (const float*)d_in[1];
  const float* vsuf = (const float*)d_in[2];
  const float* Wq = (const float*)d_in[3];
  const float* Wk = (const float*)d_in[4];
  const float* Wv = (const float*)d_in[5];
  const float* Wo = (const float*)d_in[6];
  const int* validp = (const int*)d_in[7];
  float* out = (float*)d_out;

  // workspace layout (96MB peak, regions aliased across phases)
  char* W = (char*)d_ws;
  u16* Hbf  = (u16*)(W + 0);                     // 16MB  (dead after QKV gemm)
  u16* WqT  = (u16*)(W + ((size_t)16 << 20));    // 32MB  (WqT|WkT|WvT contiguous [6144][4096])
  u16* WkT  = (u16*)(W + ((size_t)48 << 20));    // 8MB
  u16* WvT  = (u16*)(W + ((size_t)56 << 20));    // 8MB
  u16* Qbf0 = (u16*)(W + ((size_t)64 << 20));    // 16MB  (dead after rope)
  u16* K0bf = (u16*)(W + ((size_t)80 << 20));    // 4MB
  u16* V0bf = (u16*)(W + ((size_t)84 << 20));    // 4MB
  u16* Kbf  = (u16*)(W + ((size_t)88 << 20));    // 4MB
  u16* Vt   = (u16*)(W + ((size_t)92 << 20));    // 4MB
  u16* Qbf  = (u16*)(W + 0);                     // alias Hbf
  u16* WoT  = (u16*)(W + ((size_t)16 << 20));    // alias WqT
  u16* AObf = (u16*)(W + ((size_t)64 << 20));    // alias Qbf0

  // 1. convert hidden -> bf16
  convert_h<<<(MTOT * HIDDEN / 4 + 255) / 256, 256, 0, stream>>>(hidden, Hbf, MTOT * HIDDEN / 4);
  // 2. transpose+convert projection weights (B^T for gemm)
  transpose_w<<<dim3(64, 64), 256, 0, stream>>>(Wq, WqT, HIDDEN, NH * HD);
  transpose_w<<<dim3(16, 64), 256, 0, stream>>>(Wk, WkT, HIDDEN, NKV * HD);
  transpose_w<<<dim3(16, 64), 256, 0, stream>>>(Wv, WvT, HIDDEN, NKV * HD);
  // 3. fused QKV projection: N = 4096+1024+1024, bf16 out (256x256 tiles)
  gemm_bt<true><<<dim3(24, 8), 512, 0, stream>>>(
      Hbf, WqT, Qbf0, K0bf, V0bf, 6144, HIDDEN, 4096, 5120);
  // 4. Wo transpose (into dead WqT region)
  transpose_w<<<dim3(64, 64), 256, 0, stream>>>(Wo, WoT, NH * HD, HIDDEN);
  // 5. RoPE + head-major relayout (Qbf over dead Hbf)
  rope_convert<<<(MTOT * (NH + NKV) * 64 + 255) / 256, 256, 0, stream>>>(Qbf0, K0bf, Qbf, Kbf);
  // 6. V transpose to [b][kvh][d][s]
  transpose_v<<<dim3(16, 2, BB * NKV), 256, 0, stream>>>(V0bf, Vt);
  // 7. flash MFMA attention (AObf over dead Qbf0) — 1D heavy-first grid
  attn_mfma<<<dim3(1024), 256, 0, stream>>>(Qbf, Kbf, Vt, ksuf, vsuf, AObf, validp);
  // 8. output projection (fp32 out, 256x256 tiles)
  gemm_bt<false><<<dim3(16, 8), 512, 0, stream>>>(
      AObf, WoT, out, out, out, HIDDEN, NH * HD, 4096, 4096);
}

// Round 4
// 512.353 us; speedup vs baseline: 1.3149x; 1.0510x over previous
//
#include <hip/hip_runtime.h>

#define HIDDEN 4096
#define NH 32
#define NKV 8
#define HD 128
#define LCK 3
#define BB 2
#define SS 1024
#define MTOT (BB * SS)  // 2048

typedef unsigned short u16;
typedef __attribute__((ext_vector_type(8))) short s16x8;   // 8 bf16 (4 VGPRs)
typedef __attribute__((ext_vector_type(4))) short s16x4;   // 4 bf16 (2 VGPRs)
typedef __attribute__((ext_vector_type(4))) float f32x4;

__device__ __forceinline__ u16 f2bf(float f) {  // RNE float->bf16
  unsigned u = __builtin_bit_cast(unsigned, f);
  u += 0x7fffu + ((u >> 16) & 1u);
  return (u16)(u >> 16);
}
__device__ __forceinline__ float bf2f(u16 h) {
  return __builtin_bit_cast(float, (unsigned)h << 16);
}
// async global->LDS, 16B per lane; LDS dest = wave-uniform base + lane*16
__device__ __forceinline__ void gld16(const void* g, void* l) {
  __builtin_amdgcn_global_load_lds((const __attribute__((address_space(1))) void*)g,
                                   (__attribute__((address_space(3))) void*)l, 16, 0, 0);
}

// ---------------------------------------------------------------------------
// fp32 -> bf16 flat convert (hidden_states)
// ---------------------------------------------------------------------------
__global__ __launch_bounds__(256) void convert_h(const float* __restrict__ in,
                                                 u16* __restrict__ out, int n4) {
  int i = blockIdx.x * 256 + threadIdx.x;
  if (i >= n4) return;
  float4 v = ((const float4*)in)[i];
  uint2 o;
  o.x = (unsigned)f2bf(v.x) | ((unsigned)f2bf(v.y) << 16);
  o.y = (unsigned)f2bf(v.z) | ((unsigned)f2bf(v.w) << 16);
  ((uint2*)out)[i] = o;
}

// ---------------------------------------------------------------------------
// out[i] += P[i]  (split-K reduction, float4)
// ---------------------------------------------------------------------------
__global__ __launch_bounds__(256) void add2(float* __restrict__ out,
                                            const float* __restrict__ P, int n4) {
  int i = blockIdx.x * 256 + threadIdx.x;
  if (i >= n4) return;
  float4 a = ((const float4*)out)[i];
  float4 b = ((const float4*)P)[i];
  a.x += b.x; a.y += b.y; a.z += b.z; a.w += b.w;
  ((float4*)out)[i] = a;
}

// ---------------------------------------------------------------------------
// W [K][N] fp32  ->  Wt [N][K] bf16   (LDS tile transpose, 64x64)
// ---------------------------------------------------------------------------
__global__ __launch_bounds__(256) void transpose_w(const float* __restrict__ W,
                                                   u16* __restrict__ Wt, int K, int N) {
  __shared__ float tile[64][65];
  const int n0 = blockIdx.x * 64, k0 = blockIdx.y * 64;
  const int ty = threadIdx.x >> 6, tx = threadIdx.x & 63;
#pragma unroll
  for (int i = 0; i < 16; ++i) {
    int r = ty * 16 + i;
    tile[r][tx] = W[(size_t)(k0 + r) * N + n0 + tx];
  }
  __syncthreads();
#pragma unroll
  for (int i = 0; i < 16; ++i) {
    int r = ty * 16 + i;
    Wt[(size_t)(n0 + r) * K + k0 + tx] = f2bf(tile[tx][r]);
  }
}

// ---------------------------------------------------------------------------
// bf16 MFMA GEMM, 256x256 tile / BK=64 / 8 waves (2Mx4N) / 512 threads.
// 8-phase counted-vmcnt schedule + st_16x32 LDS swizzle.
// Round-4 schedule: ALL staging for tile kt+2 happens during kt (B-h0@P2,
// B-h1@P3, A-h0+A-h1@P4), drained by vmcnt(8) at end of kt+1 -> min slack
// 4 phases (was 3 for the P1-staged A-h1 in the previous version).
// SPLITK: gridDim.z=2 halves K; z=0 writes C0v, z=1 writes C1v (fp32).
// ---------------------------------------------------------------------------
template <bool BF16OUT, bool SPLITK>
__global__ __launch_bounds__(512, 2) void gemm_bt(
    const u16* __restrict__ A, const u16* __restrict__ Bt,
    void* C0v, void* C1v, void* C2v, int N, int K, int n1, int n2) {
  __shared__ __align__(16) char smem[131072];
  const int tid = threadIdx.x, lane = tid & 63, w = tid >> 6;
  const int wr = w >> 2, wc = w & 3;           // wave -> 128x64 C subtile
  const int col16 = lane & 15, quad = lane >> 4;
  const int kz = SPLITK ? (int)blockIdx.z : 0;
  const int Keff = SPLITK ? (K >> 1) : K;

  // XCD-aware bijective block swizzle (m204)
  const int nbx = gridDim.x;
  const int nwg = nbx * gridDim.y;
  int fid = blockIdx.y * nbx + blockIdx.x;
  {
    const int q = nwg >> 3, r = nwg & 7;
    const int xcd = fid & 7, lid = fid >> 3;
    fid = (xcd < r ? xcd * (q + 1) : r * (q + 1) + (xcd - r) * q) + lid;
  }
  const int bm = (fid / nbx) << 8, bn = (fid % nbx) << 8;

  const int rowlane = lane >> 2;
  const int collane = ((lane & 3) * 8) ^ ((lane & 32) ? 16 : 0);
  const u16* aSrc = A + (size_t)(bm + ((w >> 1) << 4) + rowlane) * K + ((w & 1) << 5) + collane +
                    (size_t)kz * Keff;
  const u16* bSrc = Bt + (size_t)(bn + ((w >> 1) << 4) + rowlane) * K + ((w & 1) << 5) + collane +
                    (size_t)kz * Keff;
  const int laneoff = (lane & 15) * 64 + (((lane >> 4) << 4) ^ ((lane & 8) << 2));
  const int NT = Keff >> 6;

#define STG(opOfs, src, buf, h, tt)                                              \
  do {                                                                           \
    gld16((src) + (size_t)((h) * 128) * K + (size_t)(tt) * 64,                   \
          smem + (buf) * 65536 + (opOfs) +                                       \
              ((((h) * 8 + (w >> 1)) * 2 + (w & 1)) << 10));                     \
    gld16((src) + (size_t)((h) * 128 + 64) * K + (size_t)(tt) * 64,              \
          smem + (buf) * 65536 + (opOfs) +                                       \
              ((((h) * 8 + 4 + (w >> 1)) * 2 + (w & 1)) << 10));                 \
  } while (0)
#define BARX asm volatile("s_barrier" ::: "memory")
#define LGK0                                                                     \
  do {                                                                           \
    asm volatile("s_waitcnt lgkmcnt(0)" ::: "memory");                           \
    __builtin_amdgcn_sched_barrier(0);                                           \
  } while (0)

  f32x4 acc[8][4];
#pragma unroll
  for (int f = 0; f < 8; ++f)
#pragma unroll
    for (int g = 0; g < 4; ++g) acc[f][g] = (f32x4){0.f, 0.f, 0.f, 0.f};

  // prologue: fully stage tiles 0 and 1 (16 loads); wait tile 0 (keep 8)
  STG(32768, bSrc, 0, 0, 0);
  STG(32768, bSrc, 0, 1, 0);
  STG(0, aSrc, 0, 0, 0);
  STG(0, aSrc, 0, 1, 0);
  STG(32768, bSrc, 1, 0, 1);
  STG(32768, bSrc, 1, 1, 1);
  STG(0, aSrc, 1, 0, 1);
  STG(0, aSrc, 1, 1, 1);
  asm volatile("s_waitcnt vmcnt(8)" ::: "memory");
  BARX;

  for (int kt = 0; kt < NT; ++kt) {
    const int buf = kt & 1;
    const char* Af = smem + buf * 65536 + wr * 16384 + laneoff;
    const char* Bf = smem + buf * 65536 + 32768 + wc * 8192 + laneoff;
    s16x8 b0[4], b1[4], a0[4], a1[4];
    // ---- P1: reads all B + A[f0-3,kk0]; no staging ----
#pragma unroll
    for (int g = 0; g < 4; ++g) {
      b0[g] = *(const s16x8*)(Bf + (g * 2 + 0) * 1024);
      b1[g] = *(const s16x8*)(Bf + (g * 2 + 1) * 1024);
    }
#pragma unroll
    for (int f = 0; f < 4; ++f) a0[f] = *(const s16x8*)(Af + (f * 2 + 0) * 1024);
    BARX; LGK0;
    __builtin_amdgcn_s_setprio(1);
#pragma unroll
    for (int f = 0; f < 4; ++f)
#pragma unroll
      for (int g = 0; g < 4; ++g)
        acc[f][g] = __builtin_amdgcn_mfma_f32_16x16x32_bf16(a0[f], b0[g], acc[f][g], 0, 0, 0);
    __builtin_amdgcn_s_setprio(0);
    BARX;
    // ---- P2: reads A[f4-7,kk0]+A[f0-3,kk1]; stage B-h0(kt+2) ----
#pragma unroll
    for (int f = 0; f < 4; ++f) a1[f] = *(const s16x8*)(Af + ((4 + f) * 2 + 0) * 1024);
#pragma unroll
    for (int f = 0; f < 4; ++f) a0[f] = *(const s16x8*)(Af + (f * 2 + 1) * 1024);
    if (kt + 2 < NT) STG(32768, bSrc, buf, 0, kt + 2);
    BARX; LGK0;
    __builtin_amdgcn_s_setprio(1);
#pragma unroll
    for (int f = 0; f < 4; ++f)
#pragma unroll
      for (int g = 0; g < 4; ++g)
        acc[4 + f][g] = __builtin_amdgcn_mfma_f32_16x16x32_bf16(a1[f], b0[g], acc[4 + f][g], 0, 0, 0);
    __builtin_amdgcn_s_setprio(0);
    BARX;
    // ---- P3: reads A[f4-7,kk1]; stage B-h1(kt+2) ----
#pragma unroll
    for (int f = 0; f < 4; ++f) a1[f] = *(const s16x8*)(Af + ((4 + f) * 2 + 1) * 1024);
    if (kt + 2 < NT) STG(32768, bSrc, buf, 1, kt + 2);
    BARX; LGK0;
    __builtin_amdgcn_s_setprio(1);
#pragma unroll
    for (int f = 0; f < 4; ++f)
#pragma unroll
      for (int g = 0; g < 4; ++g)
        acc[f][g] = __builtin_amdgcn_mfma_f32_16x16x32_bf16(a0[f], b1[g], acc[f][g], 0, 0, 0);
    __builtin_amdgcn_s_setprio(0);
    BARX;
    // ---- P4: no reads; stage A-h0+A-h1(kt+2); per-tile counted vmcnt ----
    if (kt + 2 < NT) {
      STG(0, aSrc, buf, 0, kt + 2);
      STG(0, aSrc, buf, 1, kt + 2);
    }
    BARX; LGK0;
    __builtin_amdgcn_s_setprio(1);
#pragma unroll
    for (int f = 0; f < 4; ++f)
#pragma unroll
      for (int g = 0; g < 4; ++g)
        acc[4 + f][g] = __builtin_amdgcn_mfma_f32_16x16x32_bf16(a1[f], b1[g], acc[4 + f][g], 0, 0, 0);
    __builtin_amdgcn_s_setprio(0);
    if (kt < NT - 2) asm volatile("s_waitcnt vmcnt(8)" ::: "memory");
    else if (kt == NT - 2) asm volatile("s_waitcnt vmcnt(0)" ::: "memory");
    BARX;
  }
#undef STG
#undef BARX
#undef LGK0

  float* Cf; u16* Ch; int ldc, nb;
  if (SPLITK) {
    Cf = (float*)(kz ? C1v : C0v); Ch = (u16*)Cf; ldc = N; nb = bn;
  } else if (bn < n1) { ldc = n1;      nb = bn;      Cf = (float*)C0v; Ch = (u16*)C0v; }
  else if (bn < n2)   { ldc = n2 - n1; nb = bn - n1; Cf = (float*)C1v; Ch = (u16*)C1v; }
  else                { ldc = N - n2;  nb = bn - n2; Cf = (float*)C2v; Ch = (u16*)C2v; }
#pragma unroll
  for (int f = 0; f < 8; ++f)
#pragma unroll
    for (int g = 0; g < 4; ++g)
#pragma unroll
      for (int r = 0; r < 4; ++r) {
        size_t off = (size_t)(bm + wr * 128 + f * 16 + quad * 4 + r) * ldc +
                     nb + wc * 64 + g * 16 + col16;
        if (BF16OUT) Ch[off] = f2bf(acc[f][g][r]);
        else         Cf[off] = acc[f][g][r];
      }
}

// ---------------------------------------------------------------------------
// RoPE + relayout (vectorized, fast trig):
//   Qbf0 [b][s][32][128] -> Qbf [b][h][s][128] (bf16),
//   K0bf [b][s][8][128]  -> Kbf [b][kvh][s][128]
// 16 threads per (row, head), each handles 4 rotation pairs via ushort4.
// ---------------------------------------------------------------------------
__global__ __launch_bounds__(256) void rope_convert(const u16* __restrict__ Qin,
                                                    const u16* __restrict__ Kin,
                                                    u16* __restrict__ Qout,
                                                    u16* __restrict__ Kout) {
  const int per_row = (NH + NKV) * 16;  // 640
  int idx = blockIdx.x * 256 + threadIdx.x;
  if (idx >= MTOT * per_row) return;
  int row = idx / per_row;          // b*1024 + s
  int rem = idx - row * per_row;
  int hh = rem >> 4, t4 = rem & 15;
  int s = row & (SS - 1), b = row >> 10;
  int i0 = t4 * 4;

  const u16* src; u16* dst;
  if (hh < NH) {
    src = Qin + (size_t)row * (NH * HD) + hh * HD;
    dst = Qout + (((size_t)(b * NH + hh)) * SS + s) * HD;
  } else {
    int kh = hh - NH;
    src = Kin + (size_t)row * (NKV * HD) + kh * HD;
    dst = Kout + (((size_t)(b * NKV + kh)) * SS + s) * HD;
  }
  ushort4 x0 = *(const ushort4*)(src + i0);
  ushort4 x1 = *(const ushort4*)(src + i0 + 64);
  const u16* xa0 = (const u16*)&x0;
  const u16* xa1 = (const u16*)&x1;
  ushort4 o0, o1;
  u16* oa0 = (u16*)&o0;
  u16* oa1 = (u16*)&o1;
#pragma unroll
  for (int j = 0; j < 4; ++j) {
    float invf = __expf((float)(i0 + j) * (-9.210340371976184f / 64.0f));
    float ang = (float)s * invf;
    float sv, cv;
    __sincosf(ang, &sv, &cv);
    float a0 = bf2f(xa0[j]), a1 = bf2f(xa1[j]);
    oa0[j] = f2bf(a0 * cv - a1 * sv);
    oa1[j] = f2bf(a1 * cv + a0 * sv);
  }
  *(ushort4*)(dst + i0) = o0;
  *(ushort4*)(dst + i0 + 64) = o1;
}

// ---------------------------------------------------------------------------
// V0bf [b][s][8][128] -> Vt [b][kvh][d=128][s=1024]  (bf16 tile transpose)
// ---------------------------------------------------------------------------
__global__ __launch_bounds__(256) void transpose_v(const u16* __restrict__ V0,
                                                   u16* __restrict__ Vt) {
  __shared__ u16 tile[64][65];
  const int s0 = blockIdx.x * 64, d0 = blockIdx.y * 64;
  const int bk = blockIdx.z;  // b*8 + kvh
  const int b = bk >> 3, kvh = bk & 7;
  const int ty = threadIdx.x >> 6, tx = threadIdx.x & 63;
#pragma unroll
  for (int i = 0; i < 16; ++i) {
    int r = ty * 16 + i;
    tile[r][tx] = V0[((size_t)(b * SS + s0 + r)) * (NKV * HD) + kvh * HD + d0 + tx];
  }
  __syncthreads();
#pragma unroll
  for (int i = 0; i < 16; ++i) {
    int r = ty * 16 + i;
    Vt[((size_t)bk * HD + d0 + r) * SS + s0 + tx] = tile[tx][r];
  }
}

// ---------------------------------------------------------------------------
// Flash MFMA attention: swapped-operand + LDS-staged K/V (double-buffered,
// 2-phase pipeline, 1 barrier per KV-64 tile).  (unchanged from round 3)
// ---------------------------------------------------------------------------
__global__ __launch_bounds__(256) void attn_mfma(
    const u16* __restrict__ Qbf, const u16* __restrict__ Kbf, const u16* __restrict__ Vt,
    const float* __restrict__ ksuf, const float* __restrict__ vsuf,
    u16* __restrict__ AObf, const int* __restrict__ validp) {
  __shared__ __align__(16) char Ksm[2][16384];  // [buf][k=64][dbyte=256 swz]
  __shared__ __align__(16) char Vsm[2][16384];  // [buf][d=128][kbyte=128 swz]

  const int bid = (int)blockIdx.x;
  const int qt = 63 - (bid >> 4);
  const int kvh = bid & 7, b = (bid >> 3) & 1;
  const int q0 = qt * 16;
  const int lane = threadIdx.x & 63, w = threadIdx.x >> 6;
  const int col = lane & 15, quad = lane >> 4;
  const int h = (kvh << 2) + w;
  const int valid = *validp;
  const int q = q0 + col;  // this lane's q row (state axis)

  size_t orow = ((size_t)(b * SS + q)) * (NH * HD) + h * HD;
  if (q0 >= valid) {  // block-uniform early out (no barriers executed)
    ushort4 z = {0, 0, 0, 0};
#pragma unroll
    for (int nt = 0; nt < 8; ++nt)
      *(ushort4*)(AObf + orow + 16 * nt + quad * 4) = z;
    return;
  }

  const float scale = 0.08838834764831845f;  // 1/sqrt(128)
  const u16* qptr = Qbf + (((size_t)(b * NH + h)) * SS + q) * HD;
  s16x8 qf[4];
#pragma unroll
  for (int ds = 0; ds < 4; ++ds) qf[ds] = *(const s16x8*)(qptr + ds * 32 + quad * 8);

  const u16* kbase = Kbf + ((size_t)(b * NKV + kvh)) * SS * HD;
  const u16* vbase = Vt + ((size_t)(b * NKV + kvh)) * HD * SS;

  int ksrcoff[4], vsrcoff[4];
  {
    const int kq = (w * 4 + quad) & 7;
    const int dq = (lane >> 3) & 7;
#pragma unroll
    for (int j = 0; j < 4; ++j) {
      int kl = j * 16 + w * 4 + quad;
      ksrcoff[j] = kl * HD + (((col * 16) ^ (kq << 4)) >> 1);
      int dl = j * 32 + w * 8 + (lane >> 3);
      vsrcoff[j] = dl * SS + ((((lane & 7) * 16) ^ (dq << 4)) >> 1);
    }
  }

#define STAGE(bufi, k0v)                                                        \
  do {                                                                          \
    const u16* kp_ = kbase + (size_t)(k0v)*HD;                                  \
    const u16* vp_ = vbase + (k0v);                                             \
    _Pragma("unroll") for (int j = 0; j < 4; ++j)                               \
        gld16(kp_ + ksrcoff[j], Ksm[bufi] + j * 4096 + w * 1024);               \
    _Pragma("unroll") for (int j = 0; j < 4; ++j)                               \
        gld16(vp_ + vsrcoff[j], Vsm[bufi] + j * 4096 + w * 1024);               \
  } while (0)

  float m_ = -1e30f, l_ = 0.f;
  f32x4 O_[8];
#pragma unroll
  for (int nt = 0; nt < 8; ++nt) O_[nt] = (f32x4){0.f, 0.f, 0.f, 0.f};

  const int ntiles = (q0 + 16 + 63) >> 6;  // KVBLK = 64
  const int kswz = (col & 7) << 4;

  STAGE(0, 0);
  __syncthreads();

  for (int ti = 0; ti < ntiles; ++ti) {
    const int k0 = ti * 64;
    if (ti + 1 < ntiles) STAGE((ti + 1) & 1, k0 + 64);  // prefetch next tile
    const char* Kb = Ksm[ti & 1];
    const char* Vb = Vsm[ti & 1];

    // ---- QK^T (swapped): 4 k-subtiles of 16, A = K frag from swizzled LDS ----
    f32x4 S[4];
#pragma unroll
    for (int ks = 0; ks < 4; ++ks) {
      f32x4 s = (f32x4){0.f, 0.f, 0.f, 0.f};
#pragma unroll
      for (int ds = 0; ds < 4; ++ds) {
        s16x8 kf = *(const s16x8*)(Kb + ks * 4096 + col * 256 +
                                   ((ds * 64 + quad * 16) ^ kswz));
        s = __builtin_amdgcn_mfma_f32_16x16x32_bf16(kf, qf[ds], s, 0, 0, 0);
      }
      S[ks] = s;
    }
    // ---- mask + online softmax (state per lane, q=col) ----
    float sc[16];
    float tm = -1e30f;
#pragma unroll
    for (int ks = 0; ks < 4; ++ks)
#pragma unroll
      for (int r = 0; r < 4; ++r) {
        int kg = k0 + ks * 16 + quad * 4 + r;
        float v = (kg > q) ? -1e30f : S[ks][r] * scale;
        sc[ks * 4 + r] = v;
        tm = fmaxf(tm, v);
      }
    tm = fmaxf(tm, __shfl_xor(tm, 16));
    tm = fmaxf(tm, __shfl_xor(tm, 32));
    float mn = fmaxf(m_, tm);
    float a = __expf(m_ - mn);
    float pv[16];
    float rs = 0.f;
#pragma unroll
    for (int i = 0; i < 16; ++i) {
      pv[i] = __expf(sc[i] - mn);
      rs += pv[i];
    }
    rs += __shfl_xor(rs, 16);
    rs += __shfl_xor(rs, 32);
    l_ = l_ * a + rs;
    m_ = mn;
#pragma unroll
    for (int nt = 0; nt < 8; ++nt)
#pragma unroll
      for (int r = 0; r < 4; ++r) O_[nt][r] *= a;

    // ---- PV: zero-padded B frag, A = V^T 8B frags from swizzled LDS ----
#pragma unroll
    for (int ks = 0; ks < 4; ++ks) {
      s16x8 pb;
      pb[0] = (short)f2bf(pv[ks * 4 + 0]);
      pb[1] = (short)f2bf(pv[ks * 4 + 1]);
      pb[2] = (short)f2bf(pv[ks * 4 + 2]);
      pb[3] = (short)f2bf(pv[ks * 4 + 3]);
      pb[4] = 0; pb[5] = 0; pb[6] = 0; pb[7] = 0;
#pragma unroll
      for (int nt = 0; nt < 8; ++nt) {
        s16x4 vv = *(const s16x4*)(Vb + nt * 2048 + col * 128 +
                                   ((ks * 32 + quad * 8) ^ kswz));
        s16x8 av;
        av[0] = vv[0]; av[1] = vv[1]; av[2] = vv[2]; av[3] = vv[3];
        av[4] = 0; av[5] = 0; av[6] = 0; av[7] = 0;
        O_[nt] = __builtin_amdgcn_mfma_f32_16x16x32_bf16(av, pb, O_[nt], 0, 0, 0);
      }
    }
    __syncthreads();  // drains prefetch (vmcnt 0) + releases buf for overwrite
  }
#undef STAGE

  // ---- suffix blocks (diagonal kv = q), fp32, folded into online softmax ----
  float sp[3];
#pragma unroll
  for (int j = 0; j < 3; ++j) {
    const float* kr = ksuf + ((((size_t)(b * NKV + kvh) * LCK + j)) * SS + q) * HD + quad * 8;
    float p = 0.f;
#pragma unroll
    for (int ds = 0; ds < 4; ++ds)
#pragma unroll
      for (int e = 0; e < 8; ++e) p += bf2f((u16)qf[ds][e]) * kr[ds * 32 + e];
    p += __shfl_xor(p, 16);
    p += __shfl_xor(p, 32);
    sp[j] = p * scale;
  }
  {
    float ms = fmaxf(fmaxf(sp[0], sp[1]), sp[2]);
    float mn = fmaxf(m_, ms);
    float a = __expf(m_ - mn);
    float e0 = __expf(sp[0] - mn);
    float e1 = __expf(sp[1] - mn);
    float e2 = __expf(sp[2] - mn);
    l_ = l_ * a + e0 + e1 + e2;
    const float* v0r = vsuf + ((((size_t)(b * NKV + kvh) * LCK + 0)) * SS + q) * HD + quad * 4;
    const float* v1r = v0r + (size_t)SS * HD;
    const float* v2r = v1r + (size_t)SS * HD;
#pragma unroll
    for (int nt = 0; nt < 8; ++nt) {
      float4 x0 = *(const float4*)(v0r + 16 * nt);
      float4 x1 = *(const float4*)(v1r + 16 * nt);
      float4 x2 = *(const float4*)(v2r + 16 * nt);
      O_[nt][0] = O_[nt][0] * a + e0 * x0.x + e1 * x1.x + e2 * x2.x;
      O_[nt][1] = O_[nt][1] * a + e0 * x0.y + e1 * x1.y + e2 * x2.y;
      O_[nt][2] = O_[nt][2] * a + e0 * x0.z + e1 * x1.z + e2 * x2.z;
      O_[nt][3] = O_[nt][3] * a + e0 * x0.w + e1 * x1.w + e2 * x2.w;
    }
  }

  // ---- write AObf [b][s][h][d] (bf16); rows >= valid are zero ----
  if (q >= valid) {
    ushort4 z = {0, 0, 0, 0};
#pragma unroll
    for (int nt = 0; nt < 8; ++nt)
      *(ushort4*)(AObf + orow + 16 * nt + quad * 4) = z;
  } else {
    float inv = 1.f / l_;
#pragma unroll
    for (int nt = 0; nt < 8; ++nt) {
      ushort4 o;
      o.x = f2bf(O_[nt][0] * inv);
      o.y = f2bf(O_[nt][1] * inv);
      o.z = f2bf(O_[nt][2] * inv);
      o.w = f2bf(O_[nt][3] * inv);
      *(ushort4*)(AObf + orow + 16 * nt + quad * 4) = o;
    }
  }
}

// ---------------------------------------------------------------------------
extern "C" void kernel_launch(void* const* d_in, const int* in_sizes, int n_in,
                              void* d_out, int out_size, void* d_ws, size_t ws_size,
                              hipStream_t stream) {
  const float* hidden = (const float*)d_in[0];
  const float* ksuf = (const float*)d_in[1];
  const float* vsuf = (const float*)d_in[2];
  const float* Wq = (const float*)d_in[3];
  const float* Wk = (const float*)d_in[4];
  const float* Wv = (const float*)d_in[5];
  const float* Wo = (const float*)d_in[6];
  const int* validp = (const int*)d_in[7];
  float* out = (float*)d_out;

  // workspace layout (96MB peak, regions aliased across phases)
  char* W = (char*)d_ws;
  u16* Hbf  = (u16*)(W + 0);                     // 16MB  (dead after QKV gemm)
  u16* WqT  = (u16*)(W + ((size_t)16 << 20));    // 32MB  (WqT|WkT|WvT contiguous [6144][4096])
  u16* WkT  = (u16*)(W + ((size_t)48 << 20));    // 8MB   (dead after QKV gemm)
  u16* WvT  = (u16*)(W + ((size_t)56 << 20));    // 8MB   (dead after QKV gemm)
  u16* Qbf0 = (u16*)(W + ((size_t)64 << 20));    // 16MB  (dead after rope)
  u16* K0bf = (u16*)(W + ((size_t)80 << 20));    // 4MB   (dead after rope)
  u16* V0bf = (u16*)(W + ((size_t)84 << 20));    // 4MB   (dead after transpose_v)
  u16* Kbf  = (u16*)(W + ((size_t)88 << 20));    // 4MB   (dead after attn)
  u16* Vt   = (u16*)(W + ((size_t)92 << 20));    // 4MB   (dead after attn)
  u16* Qbf  = (u16*)(W + 0);                     // alias Hbf (dead after attn)
  u16* WoT  = (u16*)(W + ((size_t)16 << 20));    // alias WqT
  u16* AObf = (u16*)(W + ((size_t)48 << 20));    // alias WkT|WvT (16MB, alive into Wo gemm)
  float* P1f = (float*)(W + ((size_t)64 << 20)); // 32MB split-K partial (over dead 64-96MB)

  // 1. convert hidden -> bf16
  convert_h<<<(MTOT * HIDDEN / 4 + 255) / 256, 256, 0, stream>>>(hidden, Hbf, MTOT * HIDDEN / 4);
  // 2. transpose+convert projection weights (B^T for gemm)
  transpose_w<<<dim3(64, 64), 256, 0, stream>>>(Wq, WqT, HIDDEN, NH * HD);
  transpose_w<<<dim3(16, 64), 256, 0, stream>>>(Wk, WkT, HIDDEN, NKV * HD);
  transpose_w<<<dim3(16, 64), 256, 0, stream>>>(Wv, WvT, HIDDEN, NKV * HD);
  // 3. fused QKV projection: N = 4096+1024+1024, bf16 out (256x256 tiles)
  gemm_bt<true, false><<<dim3(24, 8), 512, 0, stream>>>(
      Hbf, WqT, Qbf0, K0bf, V0bf, 6144, HIDDEN, 4096, 5120);
  // 4. Wo transpose (into dead WqT region)
  transpose_w<<<dim3(64, 64), 256, 0, stream>>>(Wo, WoT, NH * HD, HIDDEN);
  // 5. RoPE + head-major relayout (Qbf over dead Hbf)
  rope_convert<<<(MTOT * (NH + NKV) * 16 + 255) / 256, 256, 0, stream>>>(Qbf0, K0bf, Qbf, Kbf);
  // 6. V transpose to [b][kvh][d][s]
  transpose_v<<<dim3(16, 2, BB * NKV), 256, 0, stream>>>(V0bf, Vt);
  // 7. flash MFMA attention (AObf over dead WkT|WvT) — 1D heavy-first grid
  attn_mfma<<<dim3(1024), 256, 0, stream>>>(Qbf, Kbf, Vt, ksuf, vsuf, AObf, validp);
  // 8. output projection, split-K=2 (256 blocks): z=0 -> out, z=1 -> P1f
  gemm_bt<false, true><<<dim3(16, 8, 2), 512, 0, stream>>>(
      AObf, WoT, out, P1f, nullptr, HIDDEN, NH * HD, HIDDEN, HIDDEN);
  // 9. split-K reduction: out += P1f
  add2<<<(MTOT * HIDDEN / 4 + 255) / 256, 256, 0, stream>>>(out, P1f, MTOT * HIDDEN / 4);
}